// Round 1
// baseline (577.589 us; speedup 1.0000x reference)
//
#include <hip/hip_runtime.h>
#include <math.h>

// ContrastiveLoss: B=16384, D=64, fp32 in, scalar fp32 out.
// loss_i = logsumexp_j(sim[i,j]) - sim[i,i];  out = mean_i(loss_i)
// sim = normalize_rows(A) @ normalize_rows(B)^T / 0.07

#define NROWS 16384
#define DIM 64
#define INV_T 14.285714285714286f           // 1/0.07
#define LOG2E 1.44269504088896340736f
#define LN2   0.69314718055994530942f
#define S_CHUNKS 16                         // j-split for occupancy

// ---------------- kernel 1: row L2-normalize (wave per row) ----------------
__global__ __launch_bounds__(256) void nrm_kernel(const float* __restrict__ in,
                                                  float* __restrict__ out) {
    int wid  = (blockIdx.x * 256 + threadIdx.x) >> 6;   // row
    int lane = threadIdx.x & 63;
    float x  = in[wid * DIM + lane];
    float ss = x * x;
    #pragma unroll
    for (int m = 32; m >= 1; m >>= 1) ss += __shfl_xor(ss, m, 64);
    out[wid * DIM + lane] = x * rsqrtf(ss);
}

// ------- kernel 2: fused sim + partial sum of exp(logit - INV_T) -----------
// Each thread owns one row i of An (64 VGPRs); B rows are wave-uniform so the
// compiler emits s_load_dwordx16 and the inner loop is v_fma_f32 v,s,v.
__global__ __launch_bounds__(256) void lse_partial_kernel(
        const float* __restrict__ An, const float* __restrict__ Bn,
        float* __restrict__ partials) {
    const int jc = blockIdx.x & (S_CHUNKS - 1);
    const int rb = blockIdx.x / S_CHUNKS;
    const int i  = rb * 256 + threadIdx.x;

    float a[DIM];
    const float4* ap = (const float4*)(An + (size_t)i * DIM);
    #pragma unroll
    for (int k = 0; k < DIM / 4; ++k) {
        float4 v = ap[k];
        a[4*k+0] = v.x; a[4*k+1] = v.y; a[4*k+2] = v.z; a[4*k+3] = v.w;
    }

    const int j0 = jc * (NROWS / S_CHUNKS);
    const int j1 = j0 + (NROWS / S_CHUNKS);
    float sum = 0.0f;
    for (int j = j0; j < j1; j += 2) {                 // 2 rows/iter: ILP
        const float* __restrict__ b0 = Bn + (size_t)j * DIM;
        const float* __restrict__ b1 = b0 + DIM;
        float d0 = 0.f, d1 = 0.f;
        #pragma unroll
        for (int k = 0; k < DIM; ++k) {
            d0 = fmaf(a[k], b0[k], d0);
            d1 = fmaf(a[k], b1[k], d1);
        }
        // exp(d*INV_T - INV_T) = exp2(fma(d, INV_T*LOG2E, -INV_T*LOG2E))
        sum += __builtin_amdgcn_exp2f(fmaf(d0, INV_T * LOG2E, -INV_T * LOG2E));
        sum += __builtin_amdgcn_exp2f(fmaf(d1, INV_T * LOG2E, -INV_T * LOG2E));
    }
    partials[(size_t)jc * NROWS + i] = sum;
}

// ------- kernel 3: per-row loss = INV_T + log(sum) - diag*INV_T ------------
__global__ __launch_bounds__(256) void rowloss_kernel(
        const float* __restrict__ An, const float* __restrict__ Bn,
        const float* __restrict__ partials, float* __restrict__ rowloss) {
    int wid  = (blockIdx.x * 256 + threadIdx.x) >> 6;   // row
    int lane = threadIdx.x & 63;
    float p = An[wid * DIM + lane] * Bn[wid * DIM + lane];
    #pragma unroll
    for (int m = 32; m >= 1; m >>= 1) p += __shfl_xor(p, m, 64);
    if (lane == 0) {
        float s = 0.f;
        #pragma unroll
        for (int c = 0; c < S_CHUNKS; ++c) s += partials[(size_t)c * NROWS + wid];
        // lse = INV_T + ln(s);  v_log_f32 returns log2
        float lse = INV_T + __builtin_amdgcn_logf(s) * LN2;
        rowloss[wid] = lse - p * INV_T;
    }
}

// ------- kernel 4: deterministic mean over 16384 row losses ----------------
__global__ __launch_bounds__(1024) void mean_kernel(
        const float* __restrict__ rowloss, float* __restrict__ out) {
    float s = 0.f;
    for (int idx = threadIdx.x; idx < NROWS; idx += 1024) s += rowloss[idx];
    __shared__ float red[16];
    #pragma unroll
    for (int m = 32; m >= 1; m >>= 1) s += __shfl_xor(s, m, 64);
    if ((threadIdx.x & 63) == 0) red[threadIdx.x >> 6] = s;
    __syncthreads();
    if (threadIdx.x < 16) {
        float t = red[threadIdx.x];
        #pragma unroll
        for (int m = 8; m >= 1; m >>= 1) t += __shfl_xor(t, m, 16);
        if (threadIdx.x == 0) out[0] = t * (1.0f / NROWS);
    }
}

extern "C" void kernel_launch(void* const* d_in, const int* in_sizes, int n_in,
                              void* d_out, int out_size, void* d_ws, size_t ws_size,
                              hipStream_t stream) {
    const float* A  = (const float*)d_in[0];
    const float* Bm = (const float*)d_in[1];
    float* out = (float*)d_out;

    float* An       = (float*)d_ws;                    // 4 MiB
    float* Bn       = An + (size_t)NROWS * DIM;        // 4 MiB
    float* partials = Bn + (size_t)NROWS * DIM;        // 1 MiB
    float* rowloss  = partials + (size_t)S_CHUNKS * NROWS; // 64 KiB

    nrm_kernel<<<NROWS / 4, 256, 0, stream>>>(A,  An);
    nrm_kernel<<<NROWS / 4, 256, 0, stream>>>(Bm, Bn);
    lse_partial_kernel<<<(NROWS / 256) * S_CHUNKS, 256, 0, stream>>>(An, Bn, partials);
    rowloss_kernel<<<NROWS / 4, 256, 0, stream>>>(An, Bn, partials, rowloss);
    mean_kernel<<<1, 1024, 0, stream>>>(rowloss, out);
}

// Round 2
// 100.994 us; speedup vs baseline: 5.7191x; 5.7191x over previous
//
#include <hip/hip_runtime.h>
#include <math.h>

// ContrastiveLoss: B=16384, D=64, fp32 in, scalar fp32 out.
// loss_i = logsumexp_j(sim[i,j]) - sim[i,i];  out = mean_i(loss_i)
// sim = normalize_rows(A) @ normalize_rows(B)^T / 0.07
//
// Round 2: bf16 MFMA engine. An is pre-scaled by INV_T*LOG2E so the MFMA
// accumulator IS the exp2 argument. Row sums of exp2 accumulated per lane,
// reduced with shfl; diag computed exactly in fp32 from the raw inputs.

#define NROWS 16384
#define DIM 64
#define INV_T 14.285714285714286f           // 1/0.07
#define LOG2E 1.44269504088896340736f
#define LN2   0.69314718055994530942f
#define SCALE (INV_T * LOG2E)               // fold 1/T and log2(e) into A

#define JC    32                            // j-chunks (parallelism)
#define JPC   (NROWS / JC)                  // 512 j per chunk
#define WROWS 64                            // rows per wave (4 MFMA tiles)
#define BROWS 256                           // rows per block (4 waves)

typedef __attribute__((ext_vector_type(8))) short bf16x8;  // 8 bf16 = 4 VGPRs
typedef __attribute__((ext_vector_type(4))) float f32x4;

static __device__ __forceinline__ unsigned short f2bf(float f) {
    unsigned int u = __float_as_uint(f);
    unsigned int r = (u + 0x7fffu + ((u >> 16) & 1u)) >> 16;   // RNE
    return (unsigned short)r;
}

// ---------------- kernel 1: normalize rows -> bf16 (optionally scaled) -----
__global__ __launch_bounds__(256) void nrm_bf16_kernel(
        const float* __restrict__ in, unsigned short* __restrict__ out,
        float scale) {
    int wid  = (blockIdx.x * 256 + threadIdx.x) >> 6;   // row
    int lane = threadIdx.x & 63;
    float x  = in[wid * DIM + lane];
    float ss = x * x;
    #pragma unroll
    for (int m = 32; m >= 1; m >>= 1) ss += __shfl_xor(ss, m, 64);
    out[wid * DIM + lane] = f2bf(x * rsqrtf(ss) * scale);
}

// -------- kernel 2: MFMA sim tiles + exp2 row-sum partials -----------------
// Wave holds 64 A-rows as MFMA fragments; loops over its j-chunk loading
// B fragments straight from global (L2-resident). acc = sim*INV_T*LOG2E.
__global__ __launch_bounds__(256) void simexp_kernel(
        const unsigned short* __restrict__ Ab,
        const unsigned short* __restrict__ Bb,
        float* __restrict__ partials) {
    const int lane = threadIdx.x & 63;
    const int wid  = threadIdx.x >> 6;                  // wave in block
    const int jc   = blockIdx.x & (JC - 1);
    const int rb   = blockIdx.x / JC;
    const int i0   = rb * BROWS + wid * WROWS;          // wave's first row
    const int lr   = lane & 15;                         // fragment row/col
    const int lk   = lane >> 4;                         // k-group (×8)

    bf16x8 a[4][2];
    #pragma unroll
    for (int t = 0; t < 4; ++t) {
        const unsigned short* ap = Ab + (size_t)(i0 + t * 16 + lr) * DIM + lk * 8;
        a[t][0] = *(const bf16x8*)(ap);
        a[t][1] = *(const bf16x8*)(ap + 32);
    }

    float es[4][4];
    #pragma unroll
    for (int t = 0; t < 4; ++t)
        #pragma unroll
        for (int r = 0; r < 4; ++r) es[t][r] = 0.0f;

    const unsigned short* bp = Bb + (size_t)(jc * JPC + lr) * DIM + lk * 8;
    for (int jt = 0; jt < JPC / 16; ++jt) {
        bf16x8 b0 = *(const bf16x8*)(bp);
        bf16x8 b1 = *(const bf16x8*)(bp + 32);
        bp += 16 * DIM;
        #pragma unroll
        for (int t = 0; t < 4; ++t) {
            f32x4 acc = {0.f, 0.f, 0.f, 0.f};
            acc = __builtin_amdgcn_mfma_f32_16x16x32_bf16(a[t][0], b0, acc, 0, 0, 0);
            acc = __builtin_amdgcn_mfma_f32_16x16x32_bf16(a[t][1], b1, acc, 0, 0, 0);
            #pragma unroll
            for (int r = 0; r < 4; ++r)
                es[t][r] += __builtin_amdgcn_exp2f(acc[r]);
        }
    }

    // es[t][r] is a partial over this lane's 16-col slice of row i0+t*16+lk*4+r.
    // Sum across the 16 lanes sharing lk (xor masks 1,2,4,8 stay in-group).
    #pragma unroll
    for (int t = 0; t < 4; ++t)
        #pragma unroll
        for (int r = 0; r < 4; ++r) {
            float v = es[t][r];
            v += __shfl_xor(v, 1, 64);
            v += __shfl_xor(v, 2, 64);
            v += __shfl_xor(v, 4, 64);
            v += __shfl_xor(v, 8, 64);
            es[t][r] = v;
        }

    if (lr == 0) {                                      // lanes 0,16,32,48
        float* pout = partials + (size_t)jc * NROWS + i0;
        #pragma unroll
        for (int t = 0; t < 4; ++t) {
            f32x4 v = {es[t][0], es[t][1], es[t][2], es[t][3]};
            *(f32x4*)(pout + t * 16 + lk * 4) = v;      // rows lk*4..lk*4+3
        }
    }
}

// -------- kernel 3: per-row loss; diag from raw fp32 inputs ----------------
__global__ __launch_bounds__(256) void rowloss_kernel(
        const float* __restrict__ A, const float* __restrict__ B,
        const float* __restrict__ partials, float* __restrict__ rowloss) {
    int row  = (blockIdx.x * 256 + threadIdx.x) >> 6;
    int lane = threadIdx.x & 63;
    float a = A[row * DIM + lane];
    float b = B[row * DIM + lane];
    float saa = a * a, sbb = b * b, sab = a * b;
    #pragma unroll
    for (int m = 32; m >= 1; m >>= 1) {
        saa += __shfl_xor(saa, m, 64);
        sbb += __shfl_xor(sbb, m, 64);
        sab += __shfl_xor(sab, m, 64);
    }
    if (lane == 0) {
        float S = 0.f;
        #pragma unroll
        for (int c = 0; c < JC; ++c) S += partials[(size_t)c * NROWS + row];
        float diag = sab * rsqrtf(saa * sbb);           // exact fp32 cos-sim
        // natural lse = ln(S) = LN2 * log2(S); S = sum 2^(sim*INV_T*LOG2E)
        rowloss[row] = LN2 * __builtin_amdgcn_logf(S) - diag * INV_T;
    }
}

// -------- kernel 4: deterministic mean over 16384 row losses ---------------
__global__ __launch_bounds__(1024) void mean_kernel(
        const float* __restrict__ rowloss, float* __restrict__ out) {
    float s = 0.f;
    for (int idx = threadIdx.x; idx < NROWS; idx += 1024) s += rowloss[idx];
    __shared__ float red[16];
    #pragma unroll
    for (int m = 32; m >= 1; m >>= 1) s += __shfl_xor(s, m, 64);
    if ((threadIdx.x & 63) == 0) red[threadIdx.x >> 6] = s;
    __syncthreads();
    if (threadIdx.x < 16) {
        float t = red[threadIdx.x];
        #pragma unroll
        for (int m = 8; m >= 1; m >>= 1) t += __shfl_xor(t, m, 16);
        if (threadIdx.x == 0) out[0] = t * (1.0f / NROWS);
    }
}

extern "C" void kernel_launch(void* const* d_in, const int* in_sizes, int n_in,
                              void* d_out, int out_size, void* d_ws, size_t ws_size,
                              hipStream_t stream) {
    const float* A  = (const float*)d_in[0];
    const float* Bm = (const float*)d_in[1];
    float* out = (float*)d_out;

    unsigned short* Ab = (unsigned short*)d_ws;                 // 2 MiB
    unsigned short* Bb = Ab + (size_t)NROWS * DIM;              // 2 MiB
    float* partials    = (float*)(Bb + (size_t)NROWS * DIM);    // 2 MiB
    float* rowloss     = partials + (size_t)JC * NROWS;         // 64 KiB

    nrm_bf16_kernel<<<NROWS / 4, 256, 0, stream>>>(A,  Ab, SCALE);
    nrm_bf16_kernel<<<NROWS / 4, 256, 0, stream>>>(Bm, Bb, 1.0f);
    simexp_kernel<<<(NROWS / BROWS) * JC, 256, 0, stream>>>(Ab, Bb, partials);
    rowloss_kernel<<<NROWS / 4, 256, 0, stream>>>(A, Bm, partials, rowloss);
    mean_kernel<<<1, 1024, 0, stream>>>(rowloss, out);
}